// Round 2
// baseline (76.232 us; speedup 1.0000x reference)
//
#include <hip/hip_runtime.h>

// Correlation layer, specialized: s1=2, s2=1, d=4 -> integer even sampling,
// bilinear weights exactly 0 -> pure gather:
// out[b, j*9+i, h1, w1] = (1/256) * sum_c x1[b,c,2h1,2w1] * x2[b,c,2(h1+j-4),2(w1+i-4)]
// (zero when displaced downsampled position is outside the 24x24 grid)

constexpr int NB = 16, NC = 256, NH = 48, NW = 48;
constexpr int H1 = 24, W1 = 24;
constexpr int NK = 81;
constexpr int CSPLIT = 16;            // channel split across blocks
constexpr int CPB = NC / CSPLIT;      // 16 channels per block, single chunk
constexpr int TH = 4;                 // h1 rows per block; full 24 cols
constexpr int OUTSZ = NB * NK * H1 * W1;  // 746496
constexpr int HW = NH * NW;

// MODE 0: per-csplit partials to ws + deterministic reduce kernel
// MODE 1: atomicAdd fallback if ws too small
template<int MODE>
__global__ __launch_bounds__(256, 4) void corr_main(
    const float* __restrict__ x1, const float* __restrict__ x2,
    float* __restrict__ dst)
{
  const int t   = threadIdx.x;
  const int h1t = blockIdx.x;         // 0..5
  const int b   = blockIdx.y;         // 0..15
  const int cz  = blockIdx.z;         // 0..15
  const int h1base = h1t * TH;
  const int cb = cz * CPB;

  __shared__ float s1[CPB][TH][24];   // 6 KB  (x1 downsampled tile)
  __shared__ float s2[CPB][12][36];   // 27 KB (x2 downsampled window, 32 data cols, stride 36)

  // ---- stage x2: rows h1base-4..h1base+7 (12), cols -4..27 (32), zero-padded ----
  {
    const int x  = t & 31;            // 0..31
    const int rh = t >> 5;            // 0..7
    const int xs = x - 4;
    const bool xv = (xs >= 0) && (xs < W1);
    const float* p2 = x2 + (size_t)(b * NC + cb) * HW;
    auto stage = [&](int r) {
      const int ys = h1base - 4 + r;
      const bool v = xv && (ys >= 0) && (ys < H1);
      const long g = (long)(2 * ys) * NW + 2 * xs;
      #pragma unroll
      for (int c = 0; c < CPB; ++c)
        s2[c][r][x] = v ? p2[g + (long)c * HW] : 0.f;
    };
    stage(rh);
    if (rh < 4) stage(rh + 8);
  }
  // ---- stage x1: 16c x 4h x 24w = 1536, 192 threads x 8 loads ----
  if (t < 192) {
    const int w  = t % 24;
    const int hc = t / 24;            // 0..7
    const int hh = hc & 3;
    const int c0 = (hc >> 2) * 8;     // 0 or 8
    const float* p1 = x1 + (size_t)(b * NC + cb + c0) * HW
                        + (size_t)(2 * (h1base + hh)) * NW + 2 * w;
    #pragma unroll
    for (int c = 0; c < 8; ++c)
      s1[c0 + c][hh][w] = p1[(size_t)c * HW];
  }
  __syncthreads();

  // ---- compute: lanes = (h1l 4) x (j 9) x (wg 6) = 216 active of 256 ----
  const int h1l = t / 54;
  const int rr  = t % 54;
  const int j   = rr / 6;
  const int wg  = rr % 6;
  if (t >= 216) return;

  float acc[9][4];
  #pragma unroll
  for (int i = 0; i < 9; ++i) { acc[i][0]=0.f; acc[i][1]=0.f; acc[i][2]=0.f; acc[i][3]=0.f; }

  #pragma unroll
  for (int c = 0; c < CPB; ++c) {
    const float4 a4 = *(const float4*)&s1[c][h1l][wg * 4];
    const float* xr = &s2[c][h1l + j][wg * 4];
    const float4 b0 = *(const float4*)&xr[0];
    const float4 b1 = *(const float4*)&xr[4];
    const float4 b2 = *(const float4*)&xr[8];
    const float av[4]  = {a4.x, a4.y, a4.z, a4.w};
    const float xw[12] = {b0.x, b0.y, b0.z, b0.w, b1.x, b1.y, b1.z, b1.w,
                          b2.x, b2.y, b2.z, b2.w};
    #pragma unroll
    for (int i = 0; i < 9; ++i)
      #pragma unroll
      for (int w = 0; w < 4; ++w)
        acc[i][w] = fmaf(av[w], xw[w + i], acc[i][w]);
  }

  const int h1 = h1base + h1l;
  const int w1 = wg * 4;
  if (MODE == 0) {
    float* base = dst + (size_t)cz * OUTSZ + (size_t)b * NK * (H1 * W1);
    #pragma unroll
    for (int i = 0; i < 9; ++i) {
      const int k = j * 9 + i;
      *(float4*)&base[(k * H1 + h1) * W1 + w1] =
          make_float4(acc[i][0], acc[i][1], acc[i][2], acc[i][3]);
    }
  } else {
    #pragma unroll
    for (int i = 0; i < 9; ++i) {
      const int k = j * 9 + i;
      #pragma unroll
      for (int w = 0; w < 4; ++w)
        atomicAdd(&dst[((size_t)(b * NK + k) * H1 + h1) * W1 + w1 + w],
                  acc[i][w] * (1.f / 256.f));
    }
  }
}

__global__ __launch_bounds__(256) void corr_reduce(const float* __restrict__ part,
                                                   float* __restrict__ out)
{
  const int n4 = OUTSZ / 4;           // 186624
  const int i = blockIdx.x * 256 + threadIdx.x;
  if (i >= n4) return;
  float4 s = make_float4(0.f, 0.f, 0.f, 0.f);
  #pragma unroll
  for (int cz = 0; cz < CSPLIT; ++cz) {
    const float4 v = ((const float4*)part)[(size_t)cz * n4 + i];
    s.x += v.x; s.y += v.y; s.z += v.z; s.w += v.w;
  }
  const float sc = 1.f / (float)NC;
  s.x *= sc; s.y *= sc; s.z *= sc; s.w *= sc;
  ((float4*)out)[i] = s;
}

extern "C" void kernel_launch(void* const* d_in, const int* in_sizes, int n_in,
                              void* d_out, int out_size, void* d_ws, size_t ws_size,
                              hipStream_t stream) {
  const float* x1 = (const float*)d_in[0];
  const float* x2 = (const float*)d_in[1];
  float* out = (float*)d_out;

  const size_t need = (size_t)CSPLIT * OUTSZ * sizeof(float);  // ~47.8 MB
  const dim3 grid(H1 / TH, NB, CSPLIT);   // (6, 16, 16)
  if (ws_size >= need) {
    float* part = (float*)d_ws;
    corr_main<0><<<grid, 256, 0, stream>>>(x1, x2, part);
    corr_reduce<<<(OUTSZ / 4 + 255) / 256, 256, 0, stream>>>(part, out);
  } else {
    hipMemsetAsync(d_out, 0, (size_t)OUTSZ * sizeof(float), stream);
    corr_main<1><<<grid, 256, 0, stream>>>(x1, x2, out);
  }
}

// Round 3
// 43.123 us; speedup vs baseline: 1.7678x; 1.7678x over previous
//
#include <hip/hip_runtime.h>

// Correlation layer, specialized: s1=2, s2=1, d=4 -> integer even sampling,
// bilinear weights exactly 0 -> pure gather:
// out[b, j*9+i, h1, w1] = (1/256) * sum_c x1[b,c,2h1,2w1] * x2[b,c,2(h1+j-4),2(w1+i-4)]
// (zero when displaced downsampled position is outside the 24x24 grid)

constexpr int NB = 16, NC = 256, NH = 48, NW = 48;
constexpr int H1 = 24, W1 = 24, NK = 81, HW = NH * NW;
constexpr int CSPLIT = 16, CPB = 16;       // 16 channels per block (one chunk)
constexpr int TH = 8;                      // h1 rows per block -> h1t in 0..2
constexpr int OUTSZ = NB * NK * H1 * W1;   // 746496
constexpr int PPB = TH * W1 * NK;          // 15552 partial floats per block

// MODE 0: block-linear partials in ws + deterministic coalesced reduce
// MODE 1: atomicAdd fallback if ws too small
template<int MODE>
__global__ __launch_bounds__(512, 4) void corr_main(
    const float* __restrict__ x1, const float* __restrict__ x2,
    float* __restrict__ dst)
{
  const int t   = threadIdx.x;
  const int h1t = blockIdx.x;   // 0..2
  const int b   = blockIdx.y;   // 0..15
  const int cz  = blockIdx.z;   // 0..15
  const int h1base = h1t * TH;
  const int cb = cz * CPB;

  __shared__ float s1[CPB][TH][24];   // 12 KB   x1 downsampled tile
  __shared__ float s2[CPB][16][36];   // 36.9 KB x2 downsampled window (32 cols + pad)

  // ---- stage x2: 16c x 16rows x 32cols via aligned float4 (keep .x,.z) ----
  // items: c(16) x r(16) x xh(16) = 4096 = 512 threads x 8
  {
    const float* p2 = x2 + (size_t)(b * NC + cb) * HW;
    #pragma unroll
    for (int q = 0; q < 8; ++q) {
      const int idx = t + q * 512;
      const int xh = idx & 15;          // float4 slot: downsampled cols 2xh-4, 2xh-3
      const int r  = (idx >> 4) & 15;   // window row
      const int c  = idx >> 8;
      const int ys = h1base - 4 + r;
      float vx = 0.f, vz = 0.f;
      if (ys >= 0 && ys < H1 && xh >= 2 && xh <= 13) {
        const float4 v = *(const float4*)&p2[(size_t)c * HW + (size_t)(2 * ys) * NW + (4 * xh - 8)];
        vx = v.x; vz = v.z;
      }
      s2[c][r][2 * xh]     = vx;
      s2[c][r][2 * xh + 1] = vz;
    }
  }
  // ---- stage x1: 16c x 8h x 24w via aligned float4 (keep .x,.z) ----
  // items: c(16) x h(8) x xq(12) = 1536 = 512 threads x 3
  {
    const float* p1 = x1 + (size_t)(b * NC + cb) * HW;
    #pragma unroll
    for (int q = 0; q < 3; ++q) {
      const int idx = t + q * 512;
      const int xq = idx % 12;
      const int hh = (idx / 12) & 7;
      const int c  = idx / 96;
      const float4 v = *(const float4*)&p1[(size_t)c * HW
                          + (size_t)(2 * (h1base + hh)) * NW + 4 * xq];
      s1[c][hh][2 * xq]     = v.x;
      s1[c][hh][2 * xq + 1] = v.z;
    }
  }
  __syncthreads();

  // ---- compute: (h1l 8) x (j 9) x (wg 6) = 432 active of 512 ----
  const int h1l = t / 54;
  const int rr  = t % 54;
  const int j   = rr / 6;
  const int wg  = rr % 6;
  if (t >= 432) return;

  float acc[9][4];
  #pragma unroll
  for (int i = 0; i < 9; ++i) { acc[i][0]=0.f; acc[i][1]=0.f; acc[i][2]=0.f; acc[i][3]=0.f; }

  #pragma unroll 4
  for (int c = 0; c < CPB; ++c) {
    const float4 a4 = *(const float4*)&s1[c][h1l][wg * 4];
    const float* xr = &s2[c][h1l + j][wg * 4];
    const float4 b0 = *(const float4*)&xr[0];
    const float4 b1 = *(const float4*)&xr[4];
    const float4 b2 = *(const float4*)&xr[8];
    const float av[4]  = {a4.x, a4.y, a4.z, a4.w};
    const float xw[12] = {b0.x, b0.y, b0.z, b0.w, b1.x, b1.y, b1.z, b1.w,
                          b2.x, b2.y, b2.z, b2.w};
    #pragma unroll
    for (int i = 0; i < 9; ++i)
      #pragma unroll
      for (int w = 0; w < 4; ++w)
        acc[i][w] = fmaf(av[w], xw[w + i], acc[i][w]);
  }

  if (MODE == 0) {
    // block-linear partials: thread writes 144B contiguous, wave writes 9216B
    float* pb = dst + (((size_t)cz * NB + b) * 3 + h1t) * PPB + (size_t)t * 36;
    #pragma unroll
    for (int i = 0; i < 9; ++i)
      *(float4*)&pb[i * 4] = make_float4(acc[i][0], acc[i][1], acc[i][2], acc[i][3]);
  } else {
    const int h1 = h1base + h1l;
    const int w1 = wg * 4;
    #pragma unroll
    for (int i = 0; i < 9; ++i) {
      const int k = j * 9 + i;
      #pragma unroll
      for (int w = 0; w < 4; ++w)
        atomicAdd(&dst[((size_t)(b * NK + k) * H1 + h1) * W1 + w1 + w],
                  acc[i][w] * (1.f / 256.f));
    }
  }
}

// Coalesced reduce: consecutive threads read consecutive partial float4s.
__global__ __launch_bounds__(256) void corr_reduce(const float* __restrict__ part,
                                                   float* __restrict__ out)
{
  const int n = blockIdx.x * 256 + threadIdx.x;   // float4 id, 186624 total
  if (n >= OUTSZ / 4) return;
  const int i   = n % 9;                // displacement col index
  const int tp  = (n / 9) % 432;        // producer thread id
  const int h1t = (n / (9 * 432)) % 3;
  const int b   = n / (9 * 432 * 3);

  const size_t inner = (size_t)tp * 36 + i * 4;
  float4 s = make_float4(0.f, 0.f, 0.f, 0.f);
  #pragma unroll
  for (int cz = 0; cz < CSPLIT; ++cz) {
    const float4 v = *(const float4*)&part[(((size_t)cz * NB + b) * 3 + h1t) * PPB + inner];
    s.x += v.x; s.y += v.y; s.z += v.z; s.w += v.w;
  }
  const float sc = 1.f / (float)NC;
  const int h1l = tp / 54;
  const int rr  = tp % 54;
  const int j   = rr / 6;
  const int wg  = rr % 6;
  const int k   = j * 9 + i;
  const int h1  = h1t * TH + h1l;
  *(float4*)&out[(((size_t)b * NK + k) * H1 + h1) * W1 + wg * 4] =
      make_float4(s.x * sc, s.y * sc, s.z * sc, s.w * sc);
}

extern "C" void kernel_launch(void* const* d_in, const int* in_sizes, int n_in,
                              void* d_out, int out_size, void* d_ws, size_t ws_size,
                              hipStream_t stream) {
  const float* x1 = (const float*)d_in[0];
  const float* x2 = (const float*)d_in[1];
  float* out = (float*)d_out;

  const size_t need = (size_t)CSPLIT * OUTSZ * sizeof(float);  // ~47.8 MB
  const dim3 grid(H1 / TH, NB, CSPLIT);   // (3, 16, 16) = 768 blocks
  if (ws_size >= need) {
    float* part = (float*)d_ws;
    corr_main<0><<<grid, 512, 0, stream>>>(x1, x2, part);
    corr_reduce<<<(OUTSZ / 4 + 255) / 256, 256, 0, stream>>>(part, out);
  } else {
    hipMemsetAsync(d_out, 0, (size_t)OUTSZ * sizeof(float), stream);
    corr_main<1><<<grid, 512, 0, stream>>>(x1, x2, out);
  }
}